// Round 9
// baseline (730.453 us; speedup 1.0000x reference)
//
#include <hip/hip_runtime.h>
#include <hip/hip_bf16.h>
#include <math.h>

typedef __bf16 bf16;
typedef __bf16 bf16x2 __attribute__((ext_vector_type(2)));
typedef __bf16 bf16x4 __attribute__((ext_vector_type(4)));
typedef __bf16 bf16x8 __attribute__((ext_vector_type(8)));
typedef float f32x4 __attribute__((ext_vector_type(4)));

#define NNODES 50000
#define NEDGES 800000

// ---- async global->LDS, 16B per lane (lane-contiguous LDS dest required) ----
static __device__ __forceinline__ void gld_lds16(const void* g, void* l) {
    __builtin_amdgcn_global_load_lds((__attribute__((address_space(1))) void*)g,
                                     (__attribute__((address_space(3))) void*)l,
                                     16, 0, 0);
}

// ============================================================================
// dtype detect (flag=1 -> inputs are fp32)
// ============================================================================
__global__ void detect_kernel(const unsigned int* __restrict__ xw, int* __restrict__ flag)
{
    const int l = threadIdx.x;  // 64 threads
    int c = 0;
    for (int i = l; i < 4096; i += 64) {
        const unsigned int b1 = (xw[i] >> 8) & 0x7Fu;
        c += (b1 >= 0x34u && b1 <= 0x43u) ? 1 : 0;
    }
#pragma unroll
    for (int off = 32; off; off >>= 1) c += __shfl_xor(c, off);
    if (l == 0) *flag = (c < 2048) ? 1 : 0;
}

__global__ __launch_bounds__(256) void zero_out_kernel(void* out, long n, const int* __restrict__ flag)
{
    const int fp32 = *flag;
    const long i = (long)blockIdx.x * 256 + threadIdx.x;
    if (i < n) {
        if (fp32) ((float*)out)[i] = 0.f;
        else ((bf16*)out)[i] = (bf16)0.f;
    }
}

// ============================================================================
// converts: produce bf16 working copies; 4 elems/thread (float4 / bf16x4)
// ============================================================================
__global__ __launch_bounds__(256) void convert4_kernel(
    const void* __restrict__ in, bf16* __restrict__ out, int n4, const int* __restrict__ flag)
{
    const int fp32 = *flag;
    const int i = blockIdx.x * 256 + threadIdx.x;
    if (i >= n4) return;
    bf16x4 o;
    if (fp32) {
        const float4 v = ((const float4*)in)[i];
        o[0] = (bf16)v.x; o[1] = (bf16)v.y; o[2] = (bf16)v.z; o[3] = (bf16)v.w;
    } else {
        o = ((const bf16x4*)in)[i];
    }
    ((bf16x4*)out)[i] = o;
}

struct CvtBatch { const void* in[16]; bf16* out[16]; int n4[16]; };

__global__ __launch_bounds__(256) void convert_batch_kernel(CvtBatch b, const int* __restrict__ flag)
{
    const int fp32 = *flag;
    const int it = blockIdx.y;
    const int n4 = b.n4[it];
    const void* in = b.in[it];
    bf16* out = b.out[it];
    for (int i = blockIdx.x * 256 + threadIdx.x; i < n4; i += gridDim.x * 256) {
        bf16x4 o;
        if (fp32) {
            const float4 v = ((const float4*)in)[i];
            o[0] = (bf16)v.x; o[1] = (bf16)v.y; o[2] = (bf16)v.z; o[3] = (bf16)v.w;
        } else {
            o = ((const bf16x4*)in)[i];
        }
        ((bf16x4*)out)[i] = o;
    }
}

// ============================================================================
// GEMM: C[M,N] = A[M,K] * B[N,K]^T  (bf16 in/out, fp32 acc), 128x128 tile,
// BK=32, DOUBLE-BUFFERED LDS (2x16KB, same 32KB as before), ONE __syncthreads
// per K-step: stage(t+1) into buf[(t+1)&1] is issued right after the barrier,
// overlapping compute(t). Safe with plain __syncthreads: the barrier at top of
// iter t guarantees all reads of buf[(t+1)&1] (done at iter t-1) completed,
// and its implicit vmcnt(0) drain covers buf[t&1]'s loads.
// LDS layout: paired-row swizzle. Granule L (16B) = sr*8 + slot, where
// sr = row>>1 (128B super-row), slot = (((row&1)<<2)|gran) ^ (sr&7).
// Bijective; every consecutive-8-lane phase group of ds_read_b128 hits all 32
// banks (verified for all quads) -> conflict-free. Applied by pre-swizzling
// the GLOBAL source address (LDS dest stays lane-linear for global_load_lds)
// and the ds_read offsets. FUSED alpha epilogue.
// ============================================================================
__global__ __launch_bounds__(256) void gemm_bt(
    const bf16* __restrict__ A, const bf16* __restrict__ B,
    bf16* __restrict__ C, int M, int N, int K,
    const bf16* __restrict__ av, const bf16* __restrict__ dv,
    float* __restrict__ aS, float* __restrict__ aD, int H)
{
    __shared__ __align__(16) bf16 As[2][128 * 32];
    __shared__ __align__(16) bf16 Bs[2][128 * 32];
    __shared__ float sPS[128];
    __shared__ float sPD[128];
    const int tid  = threadIdx.x;
    const int lane = tid & 63;
    const int w    = tid >> 6;
    const int wm   = (w >> 1) * 64, wn = (w & 1) * 64;
    const int mBase = blockIdx.y * 128, nBase = blockIdx.x * 128;
    const int hb = nBase >> 7;   // head index of this block's columns

    f32x4 acc[4][4];
#pragma unroll
    for (int i = 0; i < 4; i++)
#pragma unroll
        for (int j = 0; j < 4; j++)
#pragma unroll
            for (int r = 0; r < 4; r++) acc[i][j][r] = 0.f;

    // staging geometry: lane fills granule L (h=0: tid, h=1: tid+256);
    // invert swizzle to find which (row, gran) this granule holds.
    const int L0 = tid,       sr0 = L0 >> 3, su0 = (L0 & 7) ^ (sr0 & 7);
    const int L1 = tid + 256, sr1 = L1 >> 3, su1 = (L1 & 7) ^ (sr1 & 7);
    const int row0 = (sr0 << 1) | (su0 >> 2), g0 = (su0 & 3) * 8;
    const int row1 = (sr1 << 1) | (su1 >> 2), g1 = (su1 & 3) * 8;
    int ra0 = mBase + row0; if (ra0 > M - 1) ra0 = M - 1;
    int ra1 = mBase + row1; if (ra1 > M - 1) ra1 = M - 1;
    const bf16* gA0 = A + (long)ra0 * K + g0;
    const bf16* gA1 = A + (long)ra1 * K + g1;
    const bf16* gB0 = B + (long)(nBase + row0) * K + g0;
    const bf16* gB1 = B + (long)(nBase + row1) * K + g1;

    const int quad = lane >> 4, l16 = lane & 15;

    // consumer offsets (elems), loop-invariant: row = base + i*16 + l16
    int oA[4], oB[4];
#pragma unroll
    for (int i = 0; i < 4; i++) {
        const int rA_ = wm + i * 16 + l16;
        const int rB_ = wn + i * 16 + l16;
        oA[i] = ((rA_ >> 1) << 6) + (((((rA_ & 1) << 2) | quad) ^ ((rA_ >> 1) & 7)) << 3);
        oB[i] = ((rB_ >> 1) << 6) + (((((rB_ & 1) << 2) | quad) ^ ((rB_ >> 1) & 7)) << 3);
    }

    if (tid < 128) { sPS[tid] = 0.f; sPD[tid] = 0.f; }

    // prologue: stage tile 0 into buf 0
    gld_lds16(gA0, &As[0][tid * 8]);
    gld_lds16(gA1, &As[0][(tid + 256) * 8]);
    gld_lds16(gB0, &Bs[0][tid * 8]);
    gld_lds16(gB1, &Bs[0][(tid + 256) * 8]);

    const int nt = K >> 5;
    for (int t = 0; t < nt; ++t) {
        __syncthreads();                       // buf[t&1] ready; t-1 reads done
        if (t + 1 < nt) {                      // prefetch overlaps compute(t)
            const int k1 = (t + 1) << 5;
            bf16* a = As[(t + 1) & 1];
            bf16* b = Bs[(t + 1) & 1];
            gld_lds16(gA0 + k1, &a[tid * 8]);
            gld_lds16(gA1 + k1, &a[(tid + 256) * 8]);
            gld_lds16(gB0 + k1, &b[tid * 8]);
            gld_lds16(gB1 + k1, &b[(tid + 256) * 8]);
        }
        const bf16* as = As[t & 1];
        const bf16* bs = Bs[t & 1];
        bf16x8 af[4], bfr[4];
#pragma unroll
        for (int i = 0; i < 4; i++) {
            af[i]  = *(const bf16x8*)&as[oA[i]];
            bfr[i] = *(const bf16x8*)&bs[oB[i]];
        }
#pragma unroll
        for (int i = 0; i < 4; i++)
#pragma unroll
            for (int j = 0; j < 4; j++)
                acc[i][j] = __builtin_amdgcn_mfma_f32_16x16x32_bf16(af[i], bfr[j], acc[i][j], 0, 0, 0);
    }

    // --- fused alpha partials: per-thread cols are wn + j*16 + l16 ---
    float aval[4], dval[4];
#pragma unroll
    for (int j = 0; j < 4; j++) {
        const int cg = nBase + wn + j * 16 + l16;
        aval[j] = (float)av[cg];
        dval[j] = (float)dv[cg];
    }
#pragma unroll
    for (int i = 0; i < 4; i++) {
#pragma unroll
        for (int r = 0; r < 4; r++) {
            float ps = 0.f, pd = 0.f;
#pragma unroll
            for (int j = 0; j < 4; j++) {
                ps += acc[i][j][r] * aval[j];
                pd += acc[i][j][r] * dval[j];
            }
#pragma unroll
            for (int off = 8; off; off >>= 1) {
                ps += __shfl_xor(ps, off);
                pd += __shfl_xor(pd, off);
            }
            if (l16 == 0) {
                const int rl = wm + i * 16 + quad * 4 + r;
                atomicAdd(&sPS[rl], ps);
                atomicAdd(&sPD[rl], pd);
            }
        }
    }

    // C/D layout: col = lane&15, row = (lane>>4)*4 + r  [m89/m91 verified]
#pragma unroll
    for (int i = 0; i < 4; i++) {
        const int row0c = mBase + wm + i * 16 + quad * 4;
#pragma unroll
        for (int j = 0; j < 4; j++) {
            const int colg = nBase + wn + j * 16 + l16;
#pragma unroll
            for (int r = 0; r < 4; r++) {
                const int row = row0c + r;
                if (row < M) C[(long)row * N + colg] = (bf16)acc[i][j][r];
            }
        }
    }

    __syncthreads();
    if (tid < 128) {
        const int row = mBase + tid;
        if (row < M) {
            aS[(long)row * H + hb] = sPS[tid];
            aD[(long)row * H + hb] = sPD[tid];
        }
    }
}

// ============================================================================
// heads GEMM (MFMA): C[M,256] = h[M,128] * Wcat[256,128]^T, same dbuf+swizzle
// structure, fused bias+relu, dtype-flagged writes into d_out sections 1,2.
// ============================================================================
__global__ __launch_bounds__(256) void heads_gemm(
    const bf16* __restrict__ A, const bf16* __restrict__ B,
    void* __restrict__ outv, const bf16* __restrict__ bias,
    const int* __restrict__ dflag, int M)
{
    __shared__ __align__(16) bf16 As[2][128 * 32];
    __shared__ __align__(16) bf16 Bs[2][128 * 32];
    const int fp32 = *dflag;
    const int tid  = threadIdx.x;
    const int lane = tid & 63;
    const int w    = tid >> 6;
    const int wm   = (w >> 1) * 64, wn = (w & 1) * 64;
    const int mBase = blockIdx.y * 128, nBase = blockIdx.x * 128;
    const int K = 128;

    f32x4 acc[4][4];
#pragma unroll
    for (int i = 0; i < 4; i++)
#pragma unroll
        for (int j = 0; j < 4; j++)
#pragma unroll
            for (int r = 0; r < 4; r++) acc[i][j][r] = 0.f;

    const int L0 = tid,       sr0 = L0 >> 3, su0 = (L0 & 7) ^ (sr0 & 7);
    const int L1 = tid + 256, sr1 = L1 >> 3, su1 = (L1 & 7) ^ (sr1 & 7);
    const int row0 = (sr0 << 1) | (su0 >> 2), g0 = (su0 & 3) * 8;
    const int row1 = (sr1 << 1) | (su1 >> 2), g1 = (su1 & 3) * 8;
    int ra0 = mBase + row0; if (ra0 > M - 1) ra0 = M - 1;
    int ra1 = mBase + row1; if (ra1 > M - 1) ra1 = M - 1;
    const bf16* gA0 = A + (long)ra0 * K + g0;
    const bf16* gA1 = A + (long)ra1 * K + g1;
    const bf16* gB0 = B + (long)(nBase + row0) * K + g0;
    const bf16* gB1 = B + (long)(nBase + row1) * K + g1;

    const int quad = lane >> 4, l16 = lane & 15;

    int oA[4], oB[4];
#pragma unroll
    for (int i = 0; i < 4; i++) {
        const int rA_ = wm + i * 16 + l16;
        const int rB_ = wn + i * 16 + l16;
        oA[i] = ((rA_ >> 1) << 6) + (((((rA_ & 1) << 2) | quad) ^ ((rA_ >> 1) & 7)) << 3);
        oB[i] = ((rB_ >> 1) << 6) + (((((rB_ & 1) << 2) | quad) ^ ((rB_ >> 1) & 7)) << 3);
    }

    gld_lds16(gA0, &As[0][tid * 8]);
    gld_lds16(gA1, &As[0][(tid + 256) * 8]);
    gld_lds16(gB0, &Bs[0][tid * 8]);
    gld_lds16(gB1, &Bs[0][(tid + 256) * 8]);

    const int nt = K >> 5;  // 4
    for (int t = 0; t < nt; ++t) {
        __syncthreads();
        if (t + 1 < nt) {
            const int k1 = (t + 1) << 5;
            bf16* a = As[(t + 1) & 1];
            bf16* b = Bs[(t + 1) & 1];
            gld_lds16(gA0 + k1, &a[tid * 8]);
            gld_lds16(gA1 + k1, &a[(tid + 256) * 8]);
            gld_lds16(gB0 + k1, &b[tid * 8]);
            gld_lds16(gB1 + k1, &b[(tid + 256) * 8]);
        }
        const bf16* as = As[t & 1];
        const bf16* bs = Bs[t & 1];
        bf16x8 af[4], bfr[4];
#pragma unroll
        for (int i = 0; i < 4; i++) {
            af[i]  = *(const bf16x8*)&as[oA[i]];
            bfr[i] = *(const bf16x8*)&bs[oB[i]];
        }
#pragma unroll
        for (int i = 0; i < 4; i++)
#pragma unroll
            for (int j = 0; j < 4; j++)
                acc[i][j] = __builtin_amdgcn_mfma_f32_16x16x32_bf16(af[i], bfr[j], acc[i][j], 0, 0, 0);
    }

#pragma unroll
    for (int j = 0; j < 4; j++) {
        const int colg = nBase + wn + j * 16 + l16;      // 0..255
        const float bv = (float)bias[colg];
        const int sec = 1 + (colg >> 7);
        const int cl  = colg & 127;
        const long sbase = (long)sec * M * 128 + cl;
#pragma unroll
        for (int i = 0; i < 4; i++) {
            const int row0c = mBase + wm + i * 16 + quad * 4;
#pragma unroll
            for (int r = 0; r < 4; r++) {
                const int row = row0c + r;
                if (row < M) {
                    const float o = fmaxf(acc[i][j][r] + bv, 0.f);
                    const long idx = sbase + (long)row * 128;
                    if (fp32) ((float*)outv)[idx] = o;
                    else ((bf16*)outv)[idx] = (bf16)o;
                }
            }
        }
    }
}

// ============================================================================
// CSR build: histogram -> hierarchical scan (3 kernels) -> fill
// ============================================================================
__global__ void hist_kernel(const int* __restrict__ dst, int* __restrict__ cnt, int E)
{
    const int e = blockIdx.x * blockDim.x + threadIdx.x;
    if (e < E) atomicAdd(&cnt[dst[e]], 1);
}

__global__ __launch_bounds__(256) void scan1_kernel(
    const int* __restrict__ cnt, int* __restrict__ rowptr, int* __restrict__ blksum, int n)
{
    __shared__ int buf[256];
    const int b = blockIdx.x, t = threadIdx.x, i = b * 256 + t;
    const int v = (i < n) ? cnt[i] : 0;
    buf[t] = v;
    __syncthreads();
    for (int off = 1; off < 256; off <<= 1) {
        const int add = (t >= off) ? buf[t - off] : 0;
        __syncthreads();
        buf[t] += add;
        __syncthreads();
    }
    if (i < n) rowptr[i + 1] = buf[t];
    if (t == 255) blksum[b] = buf[255];
    if (b == 0 && t == 0) rowptr[0] = 0;
}

__global__ __launch_bounds__(256) void scan2_kernel(int* __restrict__ blksum, int nb)
{
    __shared__ int buf[256];
    const int t = threadIdx.x;
    const int v = (t < nb) ? blksum[t] : 0;
    buf[t] = v;
    __syncthreads();
    for (int off = 1; off < 256; off <<= 1) {
        const int add = (t >= off) ? buf[t - off] : 0;
        __syncthreads();
        buf[t] += add;
        __syncthreads();
    }
    if (t < nb) blksum[t] = buf[t] - v;   // exclusive block offset
}

__global__ __launch_bounds__(256) void scan3_kernel(
    int* __restrict__ rowptr, const int* __restrict__ blksum, int n)
{
    const int b = blockIdx.x, i = b * 256 + threadIdx.x;
    if (i < n) rowptr[i + 1] += blksum[b];
}

__global__ void fill_kernel(const int* __restrict__ src, const int* __restrict__ dst,
                            const int* __restrict__ rowptr, int* __restrict__ off,
                            int* __restrict__ col, int E)
{
    const int e = blockIdx.x * blockDim.x + threadIdx.x;
    if (e < E) {
        const int d = dst[e];
        const int p = rowptr[d] + atomicAdd(&off[d], 1);
        col[p] = src[e];
    }
}

// ============================================================================
// agg for H=4, CHANNEL-SLICED, XCD-PINNED (R3-verified, 116us):
// wave = (node, head-slice); s = (bid&7)>>1 pins each slice to an XCD pair.
// Consumer: 4-edge groups of 16 lanes, 16B dwordx4 gather per lane; producer
// stores pre-shifted byte offsets. shfl_xor(16/32) merges groups. relu fused.
// ============================================================================
__global__ __launch_bounds__(256) void agg4s_kernel(
    const bf16* __restrict__ h, const float* __restrict__ asrc,
    const float* __restrict__ adst, const int* __restrict__ rowptr,
    const int* __restrict__ col, const bf16* __restrict__ bias,
    bf16* __restrict__ out, int NB)
{
    __shared__ int2 ew_s[4][64];
    const int w = threadIdx.x >> 6, lane = threadIdx.x & 63;
    const int g = lane >> 4, li = lane & 15;       // edge-group, index-in-group
    const int xcd = blockIdx.x & 7;
    const int s = xcd >> 1;                        // slice pinned to XCD pair
    const int nbi = ((blockIdx.x >> 3) << 1) | (xcd & 1);
    const int n = nbi * 4 + w;                     // NB*4 == NNODES exactly
    const float ad = adst[(long)n * 4 + s];
    const int start = rowptr[n];
    const int deg   = rowptr[n + 1] - start;
    const int total = deg + 1;                     // + virtual self-loop

    float z = 0.f;
    float acc[8];
#pragma unroll
    for (int c = 0; c < 8; c++) acc[c] = 0.f;
    const char* hbp = (const char*)h;
    const int sOff = s * 256 + li * 16;            // byte offset within row
    const int2* ews = ew_s[w];

    for (int base = 0; base < total; base += 64) {
        // producer: lane handles edge (base+lane); store (byteoff, weight)
        const int i = base + lane;
        const bool valid = i < total;
        const int sv = (i < deg) ? col[start + i] : n;
        float e = asrc[(long)sv * 4 + s] + ad;
        e = (e > 0.f) ? e : 0.2f * e;
        e = fminf(fmaxf(e, -60.f), 60.f);
        const float wv = valid ? __expf(e) : 0.f;
        ew_s[w][lane] = make_int2(sv << 10, __float_as_int(wv));
        __builtin_amdgcn_wave_barrier();
        // consumer: 4 edges/iter (group g takes edge j+g), 16B gather/lane
        const int cnt = min(64, total - base);
#pragma unroll 2
        for (int j = 0; j < cnt; j += 4) {
            const int2 v = ews[j + g];
            const float ww = __int_as_float(v.y);
            z += ww;
            const bf16x8 hv = *(const bf16x8*)(hbp + (v.x + sOff));
#pragma unroll
            for (int c = 0; c < 8; c++) acc[c] += ww * (float)hv[c];
        }
        __builtin_amdgcn_wave_barrier();
    }

    // merge the 4 edge-groups (lanes l, l+16, l+32, l+48 hold same channels)
#pragma unroll
    for (int c = 0; c < 8; c++) {
        acc[c] += __shfl_xor(acc[c], 16);
        acc[c] += __shfl_xor(acc[c], 32);
    }
    z += __shfl_xor(z, 16);
    z += __shfl_xor(z, 32);

    if (g == 0) {
        const float rz = 1.f / (z + 1e-16f);
        const bf16x8 b8 = *(const bf16x8*)(bias + s * 128 + li * 8);
        bf16x8 ov;
#pragma unroll
        for (int c = 0; c < 8; c++)
            ov[c] = (bf16)fmaxf(acc[c] * rz + (float)b8[c], 0.f);   // relu fused
        *(bf16x8*)(out + (long)n * 512 + s * 128 + li * 8) = ov;
    }
}

// ============================================================================
// agg H=1 (layer 2): R3-verified 4-edge-group consumer; dtype-flagged output
// to d_out section 0 PLUS an always-bf16 copy for the heads MFMA GEMM.
// ============================================================================
__global__ __launch_bounds__(256) void agg1g_kernel(
    const bf16* __restrict__ h, const float* __restrict__ asrc,
    const float* __restrict__ adst, const int* __restrict__ rowptr,
    const int* __restrict__ col, const bf16* __restrict__ bias,
    void* __restrict__ outv, bf16* __restrict__ hb16, const int* __restrict__ dflag)
{
    __shared__ int2 ew_s[4][64];
    const int w = threadIdx.x >> 6, lane = threadIdx.x & 63;
    const int g = lane >> 4, li = lane & 15;
    const int n = blockIdx.x * 4 + w;
    if (n >= NNODES) return;
    const int fp32out = *dflag;
    const float ad = adst[n];
    const int start = rowptr[n];
    const int deg   = rowptr[n + 1] - start;
    const int total = deg + 1;

    float z = 0.f;
    float acc[8];
#pragma unroll
    for (int c = 0; c < 8; c++) acc[c] = 0.f;
    const char* hbp = (const char*)h;
    const int sOff = li * 16;
    const int2* ews = ew_s[w];

    for (int base = 0; base < total; base += 64) {
        const int i = base + lane;
        const bool valid = i < total;
        const int sv = (i < deg) ? col[start + i] : n;
        float e = asrc[sv] + ad;
        e = (e > 0.f) ? e : 0.2f * e;
        e = fminf(fmaxf(e, -60.f), 60.f);
        const float wv = valid ? __expf(e) : 0.f;
        ew_s[w][lane] = make_int2(sv << 8, __float_as_int(wv));
        __builtin_amdgcn_wave_barrier();
        const int cnt = min(64, total - base);
#pragma unroll 2
        for (int j = 0; j < cnt; j += 4) {
            const int2 v = ews[j + g];
            const float ww = __int_as_float(v.y);
            z += ww;
            const bf16x8 hv = *(const bf16x8*)(hbp + (v.x + sOff));
#pragma unroll
            for (int c = 0; c < 8; c++) acc[c] += ww * (float)hv[c];
        }
        __builtin_amdgcn_wave_barrier();
    }

#pragma unroll
    for (int c = 0; c < 8; c++) {
        acc[c] += __shfl_xor(acc[c], 16);
        acc[c] += __shfl_xor(acc[c], 32);
    }
    z += __shfl_xor(z, 16);
    z += __shfl_xor(z, 32);

    if (g == 0) {
        const float rz = 1.f / (z + 1e-16f);
        float o[8];
#pragma unroll
        for (int c = 0; c < 8; c++)
            o[c] = acc[c] * rz + (float)bias[li * 8 + c];
        bf16x8 ovb;
#pragma unroll
        for (int c = 0; c < 8; c++) ovb[c] = (bf16)o[c];
        *(bf16x8*)(hb16 + (long)n * 128 + li * 8) = ovb;     // bf16 copy for heads
        if (fp32out) {
            float* op = (float*)outv + (long)n * 128 + li * 8;
            f32x4 o0, o1;
#pragma unroll
            for (int c = 0; c < 4; c++) { o0[c] = o[c]; o1[c] = o[c + 4]; }
            *(f32x4*)op = o0;
            *(f32x4*)(op + 4) = o1;
        } else {
            *(bf16x8*)((bf16*)outv + (long)n * 128 + li * 8) = ovb;
        }
    }
}

// ============================================================================
extern "C" void kernel_launch(void* const* d_in, const int* in_sizes, int n_in,
                              void* d_out, int out_size, void* d_ws, size_t ws_size,
                              hipStream_t stream)
{
    const int N = NNODES, E = NEDGES;
    const int* srcp = (const int*)d_in[1];
    const int* dstp = srcp + E;

    char* p0 = (char*)d_ws;
    char* p = p0;
    auto bump = [&](size_t b) { char* r = p; p += (b + 255) & ~(size_t)255; return r; };
    int*   dflag  = (int*)bump(256);
    bf16*  xc     = (bf16*)bump((size_t)N * 512 * 2);
    bf16*  W0c    = (bf16*)bump(262144 * 2);
    bf16*  as0c   = (bf16*)bump(512 * 2);
    bf16*  ad0c   = (bf16*)bump(512 * 2);
    bf16*  b0c    = (bf16*)bump(512 * 2);
    bf16*  W1c    = (bf16*)bump(262144 * 2);
    bf16*  as1c   = (bf16*)bump(512 * 2);
    bf16*  ad1c   = (bf16*)bump(512 * 2);
    bf16*  b1c    = (bf16*)bump(512 * 2);
    bf16*  W2c    = (bf16*)bump(65536 * 2);
    bf16*  as2c   = (bf16*)bump(128 * 2);
    bf16*  ad2c   = (bf16*)bump(128 * 2);
    bf16*  b2c    = (bf16*)bump(128 * 2);
    bf16*  Wcat   = (bf16*)bump(32768 * 2);      // [Wv;Wt] 256x128
    bf16*  bcat   = (bf16*)bump(256 * 2);        // [bv;bt]
    int*   cnt    = (int*)bump((size_t)N * 4);
    int*   offs   = (int*)bump((size_t)N * 4);
    int*   rowptr = (int*)bump((size_t)(N + 1) * 4);
    int*   blksum = (int*)bump(256 * 4);
    int*   colarr = (int*)bump((size_t)E * 4);
    float* alphaS = (float*)bump((size_t)N * 4 * 4);
    float* alphaD = (float*)bump((size_t)N * 4 * 4);
    bf16*  bufA   = (bf16*)bump((size_t)N * 512 * 2);
    bf16*  bufB   = (bf16*)bump((size_t)N * 512 * 2);
    bf16*  hb16   = (bf16*)bump((size_t)N * 128 * 2);
    const size_t need = (size_t)(p - p0);

    detect_kernel<<<1, 64, 0, stream>>>((const unsigned int*)d_in[0], dflag);

    if (need > ws_size) {  // diagnostic fallback: zero output
        zero_out_kernel<<<((long)out_size + 255) / 256, 256, 0, stream>>>(d_out, out_size, dflag);
        return;
    }

    // convert all float tensors to bf16 working copies (4 elems/thread)
    convert4_kernel<<<(N * 512 / 4 + 255) / 256, 256, 0, stream>>>(d_in[0], xc, N * 512 / 4, dflag);
    CvtBatch cb;
    const void* ins[16] = {d_in[2], d_in[3], d_in[4], d_in[5], d_in[6], d_in[7], d_in[8], d_in[9],
                           d_in[10], d_in[11], d_in[12], d_in[13], d_in[14], d_in[15], d_in[16], d_in[17]};
    bf16* outs[16] = {W0c, as0c, ad0c, b0c, W1c, as1c, ad1c, b1c,
                      W2c, as2c, ad2c, b2c, Wcat, bcat, Wcat + 16384, bcat + 128};
    const int ns4[16] = {65536, 128, 128, 128, 65536, 128, 128, 128,
                         16384, 32, 32, 32, 4096, 32, 4096, 32};
    for (int i = 0; i < 16; i++) { cb.in[i] = ins[i]; cb.out[i] = outs[i]; cb.n4[i] = ns4[i]; }
    convert_batch_kernel<<<dim3(64, 16), 256, 0, stream>>>(cb, dflag);

    // CSR by destination
    const int nb = (N + 255) / 256;  // 196
    hipMemsetAsync(cnt, 0, (size_t)N * 4, stream);
    hipMemsetAsync(offs, 0, (size_t)N * 4, stream);
    hist_kernel<<<(E + 255) / 256, 256, 0, stream>>>(dstp, cnt, E);
    scan1_kernel<<<nb, 256, 0, stream>>>(cnt, rowptr, blksum, N);
    scan2_kernel<<<1, 256, 0, stream>>>(blksum, nb);
    scan3_kernel<<<nb, 256, 0, stream>>>(rowptr, blksum, N);
    fill_kernel<<<(E + 255) / 256, 256, 0, stream>>>(srcp, dstp, rowptr, offs, colarr, E);

    const int NB = N / 4;  // 12500 node-blocks (4 nodes each), N%4==0

    // Layer 0   (gemm grid: x = N-tiles (heads), y = M-tiles; alpha fused)
    dim3 g0(4, (N + 127) / 128);
    gemm_bt<<<g0, 256, 0, stream>>>(xc, W0c, bufA, N, 512, 512,
                                    as0c, ad0c, alphaS, alphaD, 4);
    agg4s_kernel<<<NB * 4, 256, 0, stream>>>(bufA, alphaS, alphaD, rowptr, colarr, b0c, bufB, NB);

    // Layer 1
    gemm_bt<<<g0, 256, 0, stream>>>(bufB, W1c, bufA, N, 512, 512,
                                    as1c, ad1c, alphaS, alphaD, 4);
    agg4s_kernel<<<NB * 4, 256, 0, stream>>>(bufA, alphaS, alphaD, rowptr, colarr, b1c, bufB, NB);

    // Layer 2 (heads=1) -> d_out section 0 (dtype per flag) + bf16 copy
    dim3 g2(1, (N + 127) / 128);
    gemm_bt<<<g2, 256, 0, stream>>>(bufB, W2c, bufA, N, 128, 512,
                                    as2c, ad2c, alphaS, alphaD, 1);
    agg1g_kernel<<<(N + 3) / 4, 256, 0, stream>>>(bufA, alphaS, alphaD, rowptr, colarr, b2c,
                                                  d_out, hb16, dflag);

    // Output heads (MFMA) -> sections 1,2
    heads_gemm<<<dim3(2, (N + 127) / 128), 256, 0, stream>>>(hb16, Wcat, d_out, bcat, dflag, N);
}

// Round 10
// 709.665 us; speedup vs baseline: 1.0293x; 1.0293x over previous
//
#include <hip/hip_runtime.h>
#include <hip/hip_bf16.h>
#include <math.h>

typedef __bf16 bf16;
typedef __bf16 bf16x2 __attribute__((ext_vector_type(2)));
typedef __bf16 bf16x4 __attribute__((ext_vector_type(4)));
typedef __bf16 bf16x8 __attribute__((ext_vector_type(8)));
typedef float f32x4 __attribute__((ext_vector_type(4)));

#define NNODES 50000
#define NEDGES 800000

// ---- async global->LDS, 16B per lane (lane-contiguous LDS dest required) ----
static __device__ __forceinline__ void gld_lds16(const void* g, void* l) {
    __builtin_amdgcn_global_load_lds((__attribute__((address_space(1))) void*)g,
                                     (__attribute__((address_space(3))) void*)l,
                                     16, 0, 0);
}

// ============================================================================
// dtype detect (flag=1 -> inputs are fp32)
// ============================================================================
__global__ void detect_kernel(const unsigned int* __restrict__ xw, int* __restrict__ flag)
{
    const int l = threadIdx.x;  // 64 threads
    int c = 0;
    for (int i = l; i < 4096; i += 64) {
        const unsigned int b1 = (xw[i] >> 8) & 0x7Fu;
        c += (b1 >= 0x34u && b1 <= 0x43u) ? 1 : 0;
    }
#pragma unroll
    for (int off = 32; off; off >>= 1) c += __shfl_xor(c, off);
    if (l == 0) *flag = (c < 2048) ? 1 : 0;
}

__global__ __launch_bounds__(256) void zero_out_kernel(void* out, long n, const int* __restrict__ flag)
{
    const int fp32 = *flag;
    const long i = (long)blockIdx.x * 256 + threadIdx.x;
    if (i < n) {
        if (fp32) ((float*)out)[i] = 0.f;
        else ((bf16*)out)[i] = (bf16)0.f;
    }
}

// ============================================================================
// converts: produce bf16 working copies; 4 elems/thread (float4 / bf16x4)
// ============================================================================
__global__ __launch_bounds__(256) void convert4_kernel(
    const void* __restrict__ in, bf16* __restrict__ out, int n4, const int* __restrict__ flag)
{
    const int fp32 = *flag;
    const int i = blockIdx.x * 256 + threadIdx.x;
    if (i >= n4) return;
    bf16x4 o;
    if (fp32) {
        const float4 v = ((const float4*)in)[i];
        o[0] = (bf16)v.x; o[1] = (bf16)v.y; o[2] = (bf16)v.z; o[3] = (bf16)v.w;
    } else {
        o = ((const bf16x4*)in)[i];
    }
    ((bf16x4*)out)[i] = o;
}

struct CvtBatch { const void* in[16]; bf16* out[16]; int n4[16]; };

__global__ __launch_bounds__(256) void convert_batch_kernel(CvtBatch b, const int* __restrict__ flag)
{
    const int fp32 = *flag;
    const int it = blockIdx.y;
    const int n4 = b.n4[it];
    const void* in = b.in[it];
    bf16* out = b.out[it];
    for (int i = blockIdx.x * 256 + threadIdx.x; i < n4; i += gridDim.x * 256) {
        bf16x4 o;
        if (fp32) {
            const float4 v = ((const float4*)in)[i];
            o[0] = (bf16)v.x; o[1] = (bf16)v.y; o[2] = (bf16)v.z; o[3] = (bf16)v.w;
        } else {
            o = ((const bf16x4*)in)[i];
        }
        ((bf16x4*)out)[i] = o;
    }
}

// ============================================================================
// GEMM: C[M,N] = A[M,K] * B[N,K]^T  (bf16 in/out, fp32 acc), 128x128 tile,
// BK=64, 4 waves 2x2, 2x16 mfma 16x16x32 per K-step, global_load_lds staging,
// XOR-swizzled 128B LDS rows (R8-verified).
// XCD-AWARE REMAP (when gridDim.x==4, y padded to 392): linear id = bx+4*by;
// c=id&7, k=id>>3; panel=c+8*(k>>2), vx=k&3. All 4 column-blocks of a panel
// then share one XCD's L2 (if HW round-robins by id%8) -> A-panel fetched
// once instead of 4x. Bijective over panels 0..390; padded ids return early.
// FUSED alpha epilogue (per-row dot with av/dv from registers).
// ============================================================================
__global__ __launch_bounds__(256) void gemm_bt(
    const bf16* __restrict__ A, const bf16* __restrict__ B,
    bf16* __restrict__ C, int M, int N, int K,
    const bf16* __restrict__ av, const bf16* __restrict__ dv,
    float* __restrict__ aS, float* __restrict__ aD, int H)
{
    __shared__ __align__(16) bf16 As[128 * 64];
    __shared__ __align__(16) bf16 Bs[128 * 64];
    __shared__ float sPS[128];
    __shared__ float sPD[128];
    const int tid  = threadIdx.x;
    const int lane = tid & 63;
    const int w    = tid >> 6;
    const int wm   = (w >> 1) * 64, wn = (w & 1) * 64;

    int bx = blockIdx.x, by = blockIdx.y;
    if (gridDim.x == 4) {                 // XCD-aware panel grouping (L0/L1)
        const int id = blockIdx.x + (blockIdx.y << 2);
        const int c = id & 7, k = id >> 3;
        by = c + ((k >> 2) << 3);
        bx = k & 3;
    }
    const int mBase = by * 128, nBase = bx * 128;
    if (mBase >= M) return;               // padded panel -> whole block exits
    const int hb = nBase >> 7;            // head index of this block's columns

    f32x4 acc[4][4];
#pragma unroll
    for (int i = 0; i < 4; i++)
#pragma unroll
        for (int j = 0; j < 4; j++)
#pragma unroll
            for (int r = 0; r < 4; r++) acc[i][j][r] = 0.f;

    // staging: thread covers LDS rows rA, rA+32, rA+64, rA+96; granule tid&7.
    // source granule = (tid&7) ^ (rA&7)  (rows +32k keep row&7 = rA&7).
    const int rA   = tid >> 3;                      // 0..31
    const int gsw  = ((tid & 7) ^ (rA & 7)) * 8;    // swizzled src elem offset
    int ra0 = mBase + rA;       if (ra0 > M - 1) ra0 = M - 1;
    int ra1 = mBase + rA + 32;  if (ra1 > M - 1) ra1 = M - 1;
    int ra2 = mBase + rA + 64;  if (ra2 > M - 1) ra2 = M - 1;
    int ra3 = mBase + rA + 96;  if (ra3 > M - 1) ra3 = M - 1;
    const bf16* gA0 = A + (long)ra0 * K + gsw;
    const bf16* gA1 = A + (long)ra1 * K + gsw;
    const bf16* gA2 = A + (long)ra2 * K + gsw;
    const bf16* gA3 = A + (long)ra3 * K + gsw;
    const bf16* gB0 = B + (long)(nBase + rA) * K + gsw;
    const bf16* gB1 = B + (long)(nBase + rA + 32) * K + gsw;
    const bf16* gB2 = B + (long)(nBase + rA + 64) * K + gsw;
    const bf16* gB3 = B + (long)(nBase + rA + 96) * K + gsw;
    bf16* lA0 = &As[tid * 8];
    bf16* lA1 = &As[tid * 8 + 2048];
    bf16* lA2 = &As[tid * 8 + 4096];
    bf16* lA3 = &As[tid * 8 + 6144];
    bf16* lB0 = &Bs[tid * 8];
    bf16* lB1 = &Bs[tid * 8 + 2048];
    bf16* lB2 = &Bs[tid * 8 + 4096];
    bf16* lB3 = &Bs[tid * 8 + 6144];

    const int quad = lane >> 4, l16 = lane & 15;

    if (tid < 128) { sPS[tid] = 0.f; sPD[tid] = 0.f; }

    for (int k0 = 0; k0 < K; k0 += 64) {
        gld_lds16(gA0 + k0, lA0);
        gld_lds16(gA1 + k0, lA1);
        gld_lds16(gA2 + k0, lA2);
        gld_lds16(gA3 + k0, lA3);
        gld_lds16(gB0 + k0, lB0);
        gld_lds16(gB1 + k0, lB1);
        gld_lds16(gB2 + k0, lB2);
        gld_lds16(gB3 + k0, lB3);
        __syncthreads();
#pragma unroll
        for (int ks = 0; ks < 2; ks++) {
            const int ga = (((ks << 2) | quad) ^ (l16 & 7)) * 8;  // row&7==l16&7
            bf16x8 af[4], bfr[4];
#pragma unroll
            for (int i = 0; i < 4; i++) {
                af[i]  = *(const bf16x8*)&As[(wm + i * 16 + l16) * 64 + ga];
                bfr[i] = *(const bf16x8*)&Bs[(wn + i * 16 + l16) * 64 + ga];
            }
#pragma unroll
            for (int i = 0; i < 4; i++)
#pragma unroll
                for (int j = 0; j < 4; j++)
                    acc[i][j] = __builtin_amdgcn_mfma_f32_16x16x32_bf16(af[i], bfr[j], acc[i][j], 0, 0, 0);
        }
        __syncthreads();
    }

    // --- fused alpha partials: per-thread cols are wn + j*16 + l16 ---
    float aval[4], dval[4];
#pragma unroll
    for (int j = 0; j < 4; j++) {
        const int cg = nBase + wn + j * 16 + l16;
        aval[j] = (float)av[cg];
        dval[j] = (float)dv[cg];
    }
#pragma unroll
    for (int i = 0; i < 4; i++) {
#pragma unroll
        for (int r = 0; r < 4; r++) {
            float ps = 0.f, pd = 0.f;
#pragma unroll
            for (int j = 0; j < 4; j++) {
                ps += acc[i][j][r] * aval[j];
                pd += acc[i][j][r] * dval[j];
            }
#pragma unroll
            for (int off = 8; off; off >>= 1) {
                ps += __shfl_xor(ps, off);
                pd += __shfl_xor(pd, off);
            }
            if (l16 == 0) {
                const int rl = wm + i * 16 + quad * 4 + r;
                atomicAdd(&sPS[rl], ps);
                atomicAdd(&sPD[rl], pd);
            }
        }
    }

    // C/D layout: col = lane&15, row = (lane>>4)*4 + r  [m89/m91 verified]
#pragma unroll
    for (int i = 0; i < 4; i++) {
        const int row0 = mBase + wm + i * 16 + quad * 4;
#pragma unroll
        for (int j = 0; j < 4; j++) {
            const int colg = nBase + wn + j * 16 + l16;
#pragma unroll
            for (int r = 0; r < 4; r++) {
                const int row = row0 + r;
                if (row < M) C[(long)row * N + colg] = (bf16)acc[i][j][r];
            }
        }
    }

    __syncthreads();
    if (tid < 128) {
        const int row = mBase + tid;
        if (row < M) {
            aS[(long)row * H + hb] = sPS[tid];
            aD[(long)row * H + hb] = sPD[tid];
        }
    }
}

// ============================================================================
// heads GEMM (MFMA): C[M,256] = h[M,128] * Wcat[256,128]^T, BK=64 + swizzle,
// fused bias+relu, dtype-flagged writes into d_out sections 1,2.
// ============================================================================
__global__ __launch_bounds__(256) void heads_gemm(
    const bf16* __restrict__ A, const bf16* __restrict__ B,
    void* __restrict__ outv, const bf16* __restrict__ bias,
    const int* __restrict__ dflag, int M)
{
    __shared__ __align__(16) bf16 As[128 * 64];
    __shared__ __align__(16) bf16 Bs[128 * 64];
    const int fp32 = *dflag;
    const int tid  = threadIdx.x;
    const int lane = tid & 63;
    const int w    = tid >> 6;
    const int wm   = (w >> 1) * 64, wn = (w & 1) * 64;
    const int mBase = blockIdx.y * 128, nBase = blockIdx.x * 128;
    const int K = 128;

    f32x4 acc[4][4];
#pragma unroll
    for (int i = 0; i < 4; i++)
#pragma unroll
        for (int j = 0; j < 4; j++)
#pragma unroll
            for (int r = 0; r < 4; r++) acc[i][j][r] = 0.f;

    const int rA   = tid >> 3;
    const int gsw  = ((tid & 7) ^ (rA & 7)) * 8;
    int ra0 = mBase + rA;       if (ra0 > M - 1) ra0 = M - 1;
    int ra1 = mBase + rA + 32;  if (ra1 > M - 1) ra1 = M - 1;
    int ra2 = mBase + rA + 64;  if (ra2 > M - 1) ra2 = M - 1;
    int ra3 = mBase + rA + 96;  if (ra3 > M - 1) ra3 = M - 1;
    const bf16* gA0 = A + (long)ra0 * K + gsw;
    const bf16* gA1 = A + (long)ra1 * K + gsw;
    const bf16* gA2 = A + (long)ra2 * K + gsw;
    const bf16* gA3 = A + (long)ra3 * K + gsw;
    const bf16* gB0 = B + (long)(nBase + rA) * K + gsw;
    const bf16* gB1 = B + (long)(nBase + rA + 32) * K + gsw;
    const bf16* gB2 = B + (long)(nBase + rA + 64) * K + gsw;
    const bf16* gB3 = B + (long)(nBase + rA + 96) * K + gsw;
    bf16* lA0 = &As[tid * 8];
    bf16* lA1 = &As[tid * 8 + 2048];
    bf16* lA2 = &As[tid * 8 + 4096];
    bf16* lA3 = &As[tid * 8 + 6144];
    bf16* lB0 = &Bs[tid * 8];
    bf16* lB1 = &Bs[tid * 8 + 2048];
    bf16* lB2 = &Bs[tid * 8 + 4096];
    bf16* lB3 = &Bs[tid * 8 + 6144];

    const int quad = lane >> 4, l16 = lane & 15;

    for (int k0 = 0; k0 < K; k0 += 64) {
        gld_lds16(gA0 + k0, lA0);
        gld_lds16(gA1 + k0, lA1);
        gld_lds16(gA2 + k0, lA2);
        gld_lds16(gA3 + k0, lA3);
        gld_lds16(gB0 + k0, lB0);
        gld_lds16(gB1 + k0, lB1);
        gld_lds16(gB2 + k0, lB2);
        gld_lds16(gB3 + k0, lB3);
        __syncthreads();
#pragma unroll
        for (int ks = 0; ks < 2; ks++) {
            const int ga = (((ks << 2) | quad) ^ (l16 & 7)) * 8;
            bf16x8 af[4], bfr[4];
#pragma unroll
            for (int i = 0; i < 4; i++) {
                af[i]  = *(const bf16x8*)&As[(wm + i * 16 + l16) * 64 + ga];
                bfr[i] = *(const bf16x8*)&Bs[(wn + i * 16 + l16) * 64 + ga];
            }
#pragma unroll
            for (int i = 0; i < 4; i++)
#pragma unroll
                for (int j = 0; j < 4; j++)
                    acc[i][j] = __builtin_amdgcn_mfma_f32_16x16x32_bf16(af[i], bfr[j], acc[i][j], 0, 0, 0);
        }
        __syncthreads();
    }

#pragma unroll
    for (int j = 0; j < 4; j++) {
        const int colg = nBase + wn + j * 16 + l16;      // 0..255
        const float bv = (float)bias[colg];
        const int sec = 1 + (colg >> 7);
        const int cl  = colg & 127;
        const long sbase = (long)sec * M * 128 + cl;
#pragma unroll
        for (int i = 0; i < 4; i++) {
            const int row0 = mBase + wm + i * 16 + quad * 4;
#pragma unroll
            for (int r = 0; r < 4; r++) {
                const int row = row0 + r;
                if (row < M) {
                    const float o = fmaxf(acc[i][j][r] + bv, 0.f);
                    const long idx = sbase + (long)row * 128;
                    if (fp32) ((float*)outv)[idx] = o;
                    else ((bf16*)outv)[idx] = (bf16)o;
                }
            }
        }
    }
}

// ============================================================================
// CSR build: histogram -> hierarchical scan (3 kernels) -> fill
// ============================================================================
__global__ void hist_kernel(const int* __restrict__ dst, int* __restrict__ cnt, int E)
{
    const int e = blockIdx.x * blockDim.x + threadIdx.x;
    if (e < E) atomicAdd(&cnt[dst[e]], 1);
}

__global__ __launch_bounds__(256) void scan1_kernel(
    const int* __restrict__ cnt, int* __restrict__ rowptr, int* __restrict__ blksum, int n)
{
    __shared__ int buf[256];
    const int b = blockIdx.x, t = threadIdx.x, i = b * 256 + t;
    const int v = (i < n) ? cnt[i] : 0;
    buf[t] = v;
    __syncthreads();
    for (int off = 1; off < 256; off <<= 1) {
        const int add = (t >= off) ? buf[t - off] : 0;
        __syncthreads();
        buf[t] += add;
        __syncthreads();
    }
    if (i < n) rowptr[i + 1] = buf[t];
    if (t == 255) blksum[b] = buf[255];
    if (b == 0 && t == 0) rowptr[0] = 0;
}

__global__ __launch_bounds__(256) void scan2_kernel(int* __restrict__ blksum, int nb)
{
    __shared__ int buf[256];
    const int t = threadIdx.x;
    const int v = (t < nb) ? blksum[t] : 0;
    buf[t] = v;
    __syncthreads();
    for (int off = 1; off < 256; off <<= 1) {
        const int add = (t >= off) ? buf[t - off] : 0;
        __syncthreads();
        buf[t] += add;
        __syncthreads();
    }
    if (t < nb) blksum[t] = buf[t] - v;   // exclusive block offset
}

__global__ __launch_bounds__(256) void scan3_kernel(
    int* __restrict__ rowptr, const int* __restrict__ blksum, int n)
{
    const int b = blockIdx.x, i = b * 256 + threadIdx.x;
    if (i < n) rowptr[i + 1] += blksum[b];
}

__global__ void fill_kernel(const int* __restrict__ src, const int* __restrict__ dst,
                            const int* __restrict__ rowptr, int* __restrict__ off,
                            int* __restrict__ col, int E)
{
    const int e = blockIdx.x * blockDim.x + threadIdx.x;
    if (e < E) {
        const int d = dst[e];
        const int p = rowptr[d] + atomicAdd(&off[d], 1);
        col[p] = src[e];
    }
}

// ============================================================================
// agg for H=4, CHANNEL-SLICED, XCD-PINNED (R3-verified, 116us):
// wave = (node, head-slice); s = (bid&7)>>1 pins each slice to an XCD pair.
// Consumer: 4-edge groups of 16 lanes, 16B dwordx4 gather per lane; producer
// stores pre-shifted byte offsets. shfl_xor(16/32) merges groups. relu fused.
// ============================================================================
__global__ __launch_bounds__(256) void agg4s_kernel(
    const bf16* __restrict__ h, const float* __restrict__ asrc,
    const float* __restrict__ adst, const int* __restrict__ rowptr,
    const int* __restrict__ col, const bf16* __restrict__ bias,
    bf16* __restrict__ out, int NB)
{
    __shared__ int2 ew_s[4][64];
    const int w = threadIdx.x >> 6, lane = threadIdx.x & 63;
    const int g = lane >> 4, li = lane & 15;       // edge-group, index-in-group
    const int xcd = blockIdx.x & 7;
    const int s = xcd >> 1;                        // slice pinned to XCD pair
    const int nbi = ((blockIdx.x >> 3) << 1) | (xcd & 1);
    const int n = nbi * 4 + w;                     // NB*4 == NNODES exactly
    const float ad = adst[(long)n * 4 + s];
    const int start = rowptr[n];
    const int deg   = rowptr[n + 1] - start;
    const int total = deg + 1;                     // + virtual self-loop

    float z = 0.f;
    float acc[8];
#pragma unroll
    for (int c = 0; c < 8; c++) acc[c] = 0.f;
    const char* hbp = (const char*)h;
    const int sOff = s * 256 + li * 16;            // byte offset within row
    const int2* ews = ew_s[w];

    for (int base = 0; base < total; base += 64) {
        // producer: lane handles edge (base+lane); store (byteoff, weight)
        const int i = base + lane;
        const bool valid = i < total;
        const int sv = (i < deg) ? col[start + i] : n;
        float e = asrc[(long)sv * 4 + s] + ad;
        e = (e > 0.f) ? e : 0.2f * e;
        e = fminf(fmaxf(e, -60.f), 60.f);
        const float wv = valid ? __expf(e) : 0.f;
        ew_s[w][lane] = make_int2(sv << 10, __float_as_int(wv));
        __builtin_amdgcn_wave_barrier();
        // consumer: 4 edges/iter (group g takes edge j+g), 16B gather/lane
        const int cnt = min(64, total - base);
#pragma unroll 2
        for (int j = 0; j < cnt; j += 4) {
            const int2 v = ews[j + g];
            const float ww = __int_as_float(v.y);
            z += ww;
            const bf16x8 hv = *(const bf16x8*)(hbp + (v.x + sOff));
#pragma unroll
            for (int c = 0; c < 8; c++) acc[c] += ww * (float)hv[c];
        }
        __builtin_amdgcn_wave_barrier();
    }

    // merge the 4 edge-groups (lanes l, l+16, l+32, l+48 hold same channels)
#pragma unroll
    for (int c = 0; c < 8; c++) {
        acc[c] += __shfl_xor(acc[c], 16);
        acc[c] += __shfl_xor(acc[c], 32);
    }
    z += __shfl_xor(z, 16);
    z += __shfl_xor(z, 32);

    if (g == 0) {
        const float rz = 1.f / (z + 1e-16f);
        const bf16x8 b8 = *(const bf16x8*)(bias + s * 128 + li * 8);
        bf16x8 ov;
#pragma unroll
        for (int c = 0; c < 8; c++)
            ov[c] = (bf16)fmaxf(acc[c] * rz + (float)b8[c], 0.f);   // relu fused
        *(bf16x8*)(out + (long)n * 512 + s * 128 + li * 8) = ov;
    }
}

// ============================================================================
// agg H=1 (layer 2): R3-verified 4-edge-group consumer; dtype-flagged output
// to d_out section 0 PLUS an always-bf16 copy for the heads MFMA GEMM.
// ============================================================================
__global__ __launch_bounds__(256) void agg1g_kernel(
    const bf16* __restrict__ h, const float* __restrict__ asrc,
    const float* __restrict__ adst, const int* __restrict__ rowptr,
    const int* __restrict__ col, const bf16* __restrict__ bias,
    void* __restrict__ outv, bf16* __restrict__ hb16, const int* __restrict__ dflag)
{
    __shared__ int2 ew_s[4][64];
    const int w = threadIdx.x >> 6, lane = threadIdx.x & 63;
    const int g = lane >> 4, li = lane & 15;
    const int n = blockIdx.x * 4 + w;
    if (n >= NNODES) return;
    const int fp32out = *dflag;
    const float ad = adst[n];
    const int start = rowptr[n];
    const int deg   = rowptr[n + 1] - start;
    const int total = deg + 1;

    float z = 0.f;
    float acc[8];
#pragma unroll
    for (int c = 0; c < 8; c++) acc[c] = 0.f;
    const char* hbp = (const char*)h;
    const int sOff = li * 16;
    const int2* ews = ew_s[w];

    for (int base = 0; base < total; base += 64) {
        const int i = base + lane;
        const bool valid = i < total;
        const int sv = (i < deg) ? col[start + i] : n;
        float e = asrc[sv] + ad;
        e = (e > 0.f) ? e : 0.2f * e;
        e = fminf(fmaxf(e, -60.f), 60.f);
        const float wv = valid ? __expf(e) : 0.f;
        ew_s[w][lane] = make_int2(sv << 8, __float_as_int(wv));
        __builtin_amdgcn_wave_barrier();
        const int cnt = min(64, total - base);
#pragma unroll 2
        for (int j = 0; j < cnt; j += 4) {
            const int2 v = ews[j + g];
            const float ww = __int_as_float(v.y);
            z += ww;
            const bf16x8 hv = *(const bf16x8*)(hbp + (v.x + sOff));
#pragma unroll
            for (int c = 0; c < 8; c++) acc[c] += ww * (float)hv[c];
        }
        __builtin_amdgcn_wave_barrier();
    }

#pragma unroll
    for (int c = 0; c < 8; c++) {
        acc[c] += __shfl_xor(acc[c], 16);
        acc[c] += __shfl_xor(acc[c], 32);
    }
    z += __shfl_xor(z, 16);
    z += __shfl_xor(z, 32);

    if (g == 0) {
        const float rz = 1.f / (z + 1e-16f);
        float o[8];
#pragma unroll
        for (int c = 0; c < 8; c++)
            o[c] = acc[c] * rz + (float)bias[li * 8 + c];
        bf16x8 ovb;
#pragma unroll
        for (int c = 0; c < 8; c++) ovb[c] = (bf16)o[c];
        *(bf16x8*)(hb16 + (long)n * 128 + li * 8) = ovb;     // bf16 copy for heads
        if (fp32out) {
            float* op = (float*)outv + (long)n * 128 + li * 8;
            f32x4 o0, o1;
#pragma unroll
            for (int c = 0; c < 4; c++) { o0[c] = o[c]; o1[c] = o[c + 4]; }
            *(f32x4*)op = o0;
            *(f32x4*)(op + 4) = o1;
        } else {
            *(bf16x8*)((bf16*)outv + (long)n * 128 + li * 8) = ovb;
        }
    }
}

// ============================================================================
extern "C" void kernel_launch(void* const* d_in, const int* in_sizes, int n_in,
                              void* d_out, int out_size, void* d_ws, size_t ws_size,
                              hipStream_t stream)
{
    const int N = NNODES, E = NEDGES;
    const int* srcp = (const int*)d_in[1];
    const int* dstp = srcp + E;

    char* p0 = (char*)d_ws;
    char* p = p0;
    auto bump = [&](size_t b) { char* r = p; p += (b + 255) & ~(size_t)255; return r; };
    int*   dflag  = (int*)bump(256);
    bf16*  xc     = (bf16*)bump((size_t)N * 512 * 2);
    bf16*  W0c    = (bf16*)bump(262144 * 2);
    bf16*  as0c   = (bf16*)bump(512 * 2);
    bf16*  ad0c   = (bf16*)bump(512 * 2);
    bf16*  b0c    = (bf16*)bump(512 * 2);
    bf16*  W1c    = (bf16*)bump(262144 * 2);
    bf16*  as1c   = (bf16*)bump(512 * 2);
    bf16*  ad1c   = (bf16*)bump(512 * 2);
    bf16*  b1c    = (bf16*)bump(512 * 2);
    bf16*  W2c    = (bf16*)bump(65536 * 2);
    bf16*  as2c   = (bf16*)bump(128 * 2);
    bf16*  ad2c   = (bf16*)bump(128 * 2);
    bf16*  b2c    = (bf16*)bump(128 * 2);
    bf16*  Wcat   = (bf16*)bump(32768 * 2);      // [Wv;Wt] 256x128
    bf16*  bcat   = (bf16*)bump(256 * 2);        // [bv;bt]
    int*   cnt    = (int*)bump((size_t)N * 4);
    int*   offs   = (int*)bump((size_t)N * 4);
    int*   rowptr = (int*)bump((size_t)(N + 1) * 4);
    int*   blksum = (int*)bump(256 * 4);
    int*   colarr = (int*)bump((size_t)E * 4);
    float* alphaS = (float*)bump((size_t)N * 4 * 4);
    float* alphaD = (float*)bump((size_t)N * 4 * 4);
    bf16*  bufA   = (bf16*)bump((size_t)N * 512 * 2);
    bf16*  bufB   = (bf16*)bump((size_t)N * 512 * 2);
    bf16*  hb16   = (bf16*)bump((size_t)N * 128 * 2);
    const size_t need = (size_t)(p - p0);

    detect_kernel<<<1, 64, 0, stream>>>((const unsigned int*)d_in[0], dflag);

    if (need > ws_size) {  // diagnostic fallback: zero output
        zero_out_kernel<<<((long)out_size + 255) / 256, 256, 0, stream>>>(d_out, out_size, dflag);
        return;
    }

    // convert all float tensors to bf16 working copies (4 elems/thread)
    convert4_kernel<<<(N * 512 / 4 + 255) / 256, 256, 0, stream>>>(d_in[0], xc, N * 512 / 4, dflag);
    CvtBatch cb;
    const void* ins[16] = {d_in[2], d_in[3], d_in[4], d_in[5], d_in[6], d_in[7], d_in[8], d_in[9],
                           d_in[10], d_in[11], d_in[12], d_in[13], d_in[14], d_in[15], d_in[16], d_in[17]};
    bf16* outs[16] = {W0c, as0c, ad0c, b0c, W1c, as1c, ad1c, b1c,
                      W2c, as2c, ad2c, b2c, Wcat, bcat, Wcat + 16384, bcat + 128};
    const int ns4[16] = {65536, 128, 128, 128, 65536, 128, 128, 128,
                         16384, 32, 32, 32, 4096, 32, 4096, 32};
    for (int i = 0; i < 16; i++) { cb.in[i] = ins[i]; cb.out[i] = outs[i]; cb.n4[i] = ns4[i]; }
    convert_batch_kernel<<<dim3(64, 16), 256, 0, stream>>>(cb, dflag);

    // CSR by destination
    const int nb = (N + 255) / 256;  // 196
    hipMemsetAsync(cnt, 0, (size_t)N * 4, stream);
    hipMemsetAsync(offs, 0, (size_t)N * 4, stream);
    hist_kernel<<<(E + 255) / 256, 256, 0, stream>>>(dstp, cnt, E);
    scan1_kernel<<<nb, 256, 0, stream>>>(cnt, rowptr, blksum, N);
    scan2_kernel<<<1, 256, 0, stream>>>(blksum, nb);
    scan3_kernel<<<nb, 256, 0, stream>>>(rowptr, blksum, N);
    fill_kernel<<<(E + 255) / 256, 256, 0, stream>>>(srcp, dstp, rowptr, offs, colarr, E);

    const int NB = N / 4;  // 12500 node-blocks (4 nodes each), N%4==0

    // Layer 0   (gemm grid: x = N-tiles (heads), y = M-tiles padded to 392 for
    //            the XCD-aware panel remap; alpha fused)
    dim3 g0(4, 392);
    gemm_bt<<<g0, 256, 0, stream>>>(xc, W0c, bufA, N, 512, 512,
                                    as0c, ad0c, alphaS, alphaD, 4);
    agg4s_kernel<<<NB * 4, 256, 0, stream>>>(bufA, alphaS, alphaD, rowptr, colarr, b0c, bufB, NB);

    // Layer 1
    gemm_bt<<<g0, 256, 0, stream>>>(bufB, W1c, bufA, N, 512, 512,
                                    as1c, ad1c, alphaS, alphaD, 4);
    agg4s_kernel<<<NB * 4, 256, 0, stream>>>(bufA, alphaS, alphaD, rowptr, colarr, b1c, bufB, NB);

    // Layer 2 (heads=1) -> d_out section 0 (dtype per flag) + bf16 copy
    dim3 g2(1, (N + 127) / 128);
    gemm_bt<<<g2, 256, 0, stream>>>(bufB, W2c, bufA, N, 128, 512,
                                    as2c, ad2c, alphaS, alphaD, 1);
    agg1g_kernel<<<(N + 3) / 4, 256, 0, stream>>>(bufA, alphaS, alphaD, rowptr, colarr, b2c,
                                                  d_out, hb16, dflag);

    // Output heads (MFMA) -> sections 1,2
    heads_gemm<<<dim3(2, (N + 127) / 128), 256, 0, stream>>>(hb16, Wcat, d_out, bcat, dflag, N);
}